// Round 10
// baseline (461.704 us; speedup 1.0000x reference)
//
#include <hip/hip_runtime.h>

typedef short short8 __attribute__((ext_vector_type(8)));
typedef float floatx4 __attribute__((ext_vector_type(4)));

#define D16 16
#define KC 512
// tokens: B(8) * heads(8) * HW(4096)
#define NTOK (8 * 8 * 4096)

// workspace layout:
//   [0, 512*17*4)            : M   = K x 17 fp32  (O_tV sums | count)
//   [36864, 36864 + NTOK*2)  : idx = ushort per token

__device__ __forceinline__ unsigned short rne_bf16(float x) {
    unsigned u = __float_as_uint(x);
    return (unsigned short)((u + 0x7fffu + ((u >> 16) & 1u)) >> 16);
}
__device__ __forceinline__ float bf16_to_f32(unsigned short h) {
    return __uint_as_float(((unsigned)h) << 16);
}
// [hi16(uy) : hi16(ux)] -> bf16x2(lo=trunc(x), hi=trunc(y))
__device__ __forceinline__ unsigned pk_hi16(unsigned uy, unsigned ux) {
    return __builtin_amdgcn_perm(uy, ux, 0x07060302u);
}

// ---------------- kernel 1: nearest-code assignment ----------------
// MFMA split-bf16 scores ([kh|kr] x [ch|ch] + [kh|kr] x [cr|0], 2 MFMA)
// select top-2 candidates per token via packed-float max (code index in the
// low 9 mantissa bits); exact fp32 rescore decides. Full split precision kept
// here: argmin flips were the round-3 2e-2 failure mode.
extern "C" __global__ __launch_bounds__(256)
void vq_assign(const float* __restrict__ qkv, const float* __restrict__ cb,
               unsigned short* __restrict__ idx)
{
    __shared__ alignas(16) unsigned short s_cbh[KC * 16];  // 16 KB
    __shared__ alignas(16) unsigned short s_cbr[KC * 16];  // 16 KB
    __shared__ float s_cn[KC];                             // 2 KB  |c|^2 (full)
    __shared__ float s_kf[4][16][17];                      // 4.25 KB per-wave fp32 k tiles
    int tid = threadIdx.x;
    for (int i = tid; i < KC * 16; i += 256) {
        float x = cb[i];
        unsigned short h = rne_bf16(x);
        s_cbh[i] = h;
        s_cbr[i] = rne_bf16(x - bf16_to_f32(h));
    }
    for (int j = tid; j < KC; j += 256) {
        float s = 0.f;
#pragma unroll
        for (int d = 0; d < D16; ++d) { float c = cb[j * D16 + d]; s = fmaf(c, c, s); }
        s_cn[j] = s;
    }
    __syncthreads();

    int lane = tid & 63;
    int col = lane & 15;
    int half8 = ((lane >> 4) & 1) * 8;   // k-dim sub-block this lane covers
    bool hiHalf = lane < 32;
    int wv = tid >> 6;
    // block covers 4 waves * 4 tiles * 16 tokens = 256 tokens
    int tile0 = (blockIdx.x * 4 + wv) * 4;

    for (int t = 0; t < 4; ++t) {
        int tok0 = (tile0 + t) * 16;
        int bh = tok0 >> 12;
        const float* kbase = qkv + (size_t)bh * (48 * 4096) + 16 * 4096 + (tok0 & 4095);

        // A = [kh | kr]: lanes 0-31 carry hi(k), lanes 32-63 carry residual(k)
        short8 a8;
        {
            const float* p = kbase + (size_t)half8 * 4096 + col;
#pragma unroll
            for (int i = 0; i < 8; ++i) {
                float x = p[(size_t)i * 4096];
                unsigned short h = rne_bf16(x);
                a8[i] = hiHalf ? (short)h : (short)rne_bf16(x - bf16_to_f32(h));
                if (hiHalf) s_kf[wv][col][half8 + i] = x;  // exact fp32 copy for rescore
            }
        }
        __builtin_amdgcn_wave_barrier();

        // packed top-2 per row: score with code index stuffed in low 9 bits
        float p1[4], p2[4];
#pragma unroll
        for (int r = 0; r < 4; ++r) { p1[r] = -3.4e38f; p2[r] = -3.4e38f; }

        for (int c = 0; c < 32; ++c) {
            int code = c * 16 + col;
            short8 b1 = *(const short8*)(&s_cbh[code * 16 + half8]);  // [ch|ch]
            short8 b2 = (short8)0;
            if (hiHalf) b2 = *(const short8*)(&s_cbr[code * 16 + half8]);  // [cr|0]
            float cn2 = -0.5f * s_cn[code];
            floatx4 acc = { cn2, cn2, cn2, cn2 };
            acc = __builtin_amdgcn_mfma_f32_16x16x32_bf16(a8, b1, acc, 0, 0, 0);
            acc = __builtin_amdgcn_mfma_f32_16x16x32_bf16(a8, b2, acc, 0, 0, 0);
#pragma unroll
            for (int r = 0; r < 4; ++r) {
                unsigned sb = (__float_as_uint(acc[r]) & 0xFFFFFE00u) | (unsigned)code;
                float sp = __uint_as_float(sb);
                float old1 = p1[r];
                p1[r] = fmaxf(old1, sp);
                p2[r] = fmaxf(p2[r], fminf(old1, sp));
            }
        }
        // merge top-2 across the 16 code-columns (lanes sharing a row group)
#pragma unroll
        for (int m = 1; m < 16; m <<= 1) {
#pragma unroll
            for (int r = 0; r < 4; ++r) {
                float o1 = __shfl_xor(p1[r], m, 64);
                float o2 = __shfl_xor(p2[r], m, 64);
                float n1 = fmaxf(p1[r], o1);
                float n2 = fmaxf(fminf(p1[r], o1), fmaxf(p2[r], o2));
                p1[r] = n1; p2[r] = n2;
            }
        }
        // exact fp32 rescore of the 2 candidates; lanes with col<4 own row col
        if (col < 4) {
            int c1 = 0, c2 = 0;
#pragma unroll
            for (int r = 0; r < 4; ++r) {
                if (col == r) {
                    c1 = (int)(__float_as_uint(p1[r]) & 511u);
                    c2 = (int)(__float_as_uint(p2[r]) & 511u);
                }
            }
            int tokrow = (lane >> 4) * 4 + col;
            const float* kf = &s_kf[wv][tokrow][0];
            const float* cb1 = cb + c1 * D16;
            const float* cb2 = cb + c2 * D16;
            float dot1 = 0.f, dot2 = 0.f;
#pragma unroll
            for (int d = 0; d < D16; ++d) {
                float kx = kf[d];
                dot1 = fmaf(kx, cb1[d], dot1);
                dot2 = fmaf(kx, cb2[d], dot2);
            }
            float d1 = fmaf(-2.f, dot1, s_cn[c1]);
            float d2 = fmaf(-2.f, dot2, s_cn[c2]);
            int jw = (d2 < d1 || (d2 == d1 && c2 < c1)) ? c2 : c1;
            idx[tok0 + tokrow] = (unsigned short)jw;
        }
        __builtin_amdgcn_wave_barrier();
    }
}

// ---------------- kernel 2: segment sum of v + counts ----------------
// grid 512: 512 tokens/block; flush skips zero-count rows (lambda=1 -> ~37%).
extern "C" __global__ __launch_bounds__(256)
void vq_segsum(const float* __restrict__ qkv, const unsigned short* __restrict__ idx,
               float* __restrict__ M)
{
    __shared__ float s_acc[KC * 17];   // 34.8 KB
    for (int i = threadIdx.x; i < KC * 17; i += 256) s_acc[i] = 0.f;
    __syncthreads();

#pragma unroll
    for (int u = 0; u < 2; ++u) {
        int n = blockIdx.x * 512 + u * 256 + threadIdx.x;
        int bh = n >> 12, hw = n & 4095;
        const float* bv = qkv + (size_t)bh * (48 * 4096) + hw + 32 * 4096;
        int bj = idx[n];
#pragma unroll
        for (int d = 0; d < D16; ++d)
            atomicAdd(&s_acc[bj * 17 + d], bv[(size_t)d * 4096]);
        atomicAdd(&s_acc[bj * 17 + 16], 1.0f);
    }
    __syncthreads();
    for (int j = threadIdx.x; j < KC; j += 256) {
        float c = s_acc[j * 17 + 16];
        if (c != 0.f) {
#pragma unroll
            for (int d = 0; d < D16; ++d)
                atomicAdd(&M[j * 17 + d], s_acc[j * 17 + d]);
            atomicAdd(&M[j * 17 + 16], c);
        }
    }
}

// ---------------- kernel 3: softmax-weighted gather (swapped-operand MFMA) ----------------
// S^T = mfma(A=[ch|cr] codebook, B=[qh|qh] q): lane holds w for (token=lane&15,
// codes ...). Codebook LDS rows PERMUTED (j = b*32 + g*8 + h*4 + r) so the two
// 16-code QK MFMAs leave each lane holding exactly its PV A-fragment (codes
// g*8..g*8+7 of the 32-block) -> no LDS writes, no cross-lane moves for w.
// w trunc-bf16 feeds BOTH PV (numerator) and den (fp32 fma) -> common-mode
// rounding cancels. cb rows padded to 40 shorts (conflict-free b128 reads).
extern "C" __global__ __launch_bounds__(256)
void vq_attend(const float* __restrict__ qkv, const float* __restrict__ cb,
               const float* __restrict__ M, float* __restrict__ out)
{
    __shared__ alignas(16) unsigned short s_cb2[KC * 40];  // 40 KB  permuted [ch|cr]
    __shared__ alignas(16) unsigned short s_mt[16 * 520];  // 16.25 KB  M^T bf16, padded
    __shared__ alignas(16) float s_cnt[KC];                // 2 KB  natural code order

    int tid = threadIdx.x;
    // stage codebook: LDS row rho (within 32-block: h*16 + m) holds actual
    // code j = b*32 + (m>>2)*8 + h*4 + (m&3); slots 0-15 = ch, 16-31 = cr.
    for (int e = tid; e < KC * 16; e += 256) {
        int rho = e >> 4, d = e & 15;
        int b = rho >> 5, w = rho & 31;
        int h = w >> 4, m = w & 15;
        int j = b * 32 + (m >> 2) * 8 + h * 4 + (m & 3);
        float x = cb[j * 16 + d];
        unsigned short hh = rne_bf16(x);
        s_cb2[rho * 40 + d] = hh;
        s_cb2[rho * 40 + 16 + d] = rne_bf16(x - bf16_to_f32(hh));
    }
    for (int i = tid; i < KC * 17; i += 256) {
        int j = i / 17, d = i - j * 17;
        float x = M[i];
        if (d == 16) s_cnt[j] = x;
        else s_mt[d * 520 + j] = rne_bf16(x);
    }
    __syncthreads();

    int lane = tid & 63;
    int col = lane & 15;   // QK: A-row (code slot) & B-col (token); PV: out d
    int g = lane >> 4;
    int wv_id = tid >> 6;
    // block covers 4 waves * 4 tiles * 16 tokens = 256 tokens
    int tile0 = (blockIdx.x * 4 + wv_id) * 4;

    for (int tp = 0; tp < 2; ++tp) {
        int tokA = (tile0 + 2 * tp) * 16;
        int tokB = tokA + 16;

        // q B-frags: lane holds qh[token=col][d=(g&1)*8 + i]
        short8 qA, qB;
        {
            const float* p = qkv + (size_t)(tokA >> 12) * (48 * 4096) + (tokA & 4095)
                           + (size_t)((g & 1) * 8) * 4096 + col;
#pragma unroll
            for (int i = 0; i < 8; ++i) qA[i] = (short)rne_bf16(p[(size_t)i * 4096]);
        }
        {
            const float* p = qkv + (size_t)(tokB >> 12) * (48 * 4096) + (tokB & 4095)
                           + (size_t)((g & 1) * 8) * 4096 + col;
#pragma unroll
            for (int i = 0; i < 8; ++i) qB[i] = (short)rne_bf16(p[(size_t)i * 4096]);
        }

        floatx4 oA = {0.f, 0.f, 0.f, 0.f}, oB = {0.f, 0.f, 0.f, 0.f};
        float denA = 0.f, denB = 0.f;

        for (int b = 0; b < 16; ++b) {
            // QK A-frags (shared between tiles): rows of the permuted codebook
            short8 A0 = *(const short8*)(&s_cb2[(b * 32 + col) * 40 + g * 8]);
            short8 A1 = *(const short8*)(&s_cb2[(b * 32 + 16 + col) * 40 + g * 8]);
            float4 cn0 = *(const float4*)(&s_cnt[b * 32 + g * 8]);
            float4 cn1 = *(const float4*)(&s_cnt[b * 32 + g * 8 + 4]);
            floatx4 z = {0.f, 0.f, 0.f, 0.f};
            floatx4 sA0 = __builtin_amdgcn_mfma_f32_16x16x32_bf16(A0, qA, z, 0, 0, 0);
            floatx4 sA1 = __builtin_amdgcn_mfma_f32_16x16x32_bf16(A1, qA, z, 0, 0, 0);
            floatx4 sB0 = __builtin_amdgcn_mfma_f32_16x16x32_bf16(A0, qB, z, 0, 0, 0);
            floatx4 sB1 = __builtin_amdgcn_mfma_f32_16x16x32_bf16(A1, qB, z, 0, 0, 0);
            // PV B-frag (shared between tiles): M^T, natural code order
            short8 mb = *(const short8*)(&s_mt[col * 520 + b * 32 + g * 8]);

            // tile A: w = trunc-bf16(exp(S)); den += w*cnt; pack PV A-frag
            union { unsigned u[4]; short8 s8; } paA, paB;
            {
                unsigned u0 = __float_as_uint(__expf(sA0[0]));
                unsigned u1 = __float_as_uint(__expf(sA0[1]));
                unsigned u2 = __float_as_uint(__expf(sA0[2]));
                unsigned u3 = __float_as_uint(__expf(sA0[3]));
                unsigned u4 = __float_as_uint(__expf(sA1[0]));
                unsigned u5 = __float_as_uint(__expf(sA1[1]));
                unsigned u6 = __float_as_uint(__expf(sA1[2]));
                unsigned u7 = __float_as_uint(__expf(sA1[3]));
                denA = fmaf(__uint_as_float(u0 & 0xffff0000u), cn0.x, denA);
                denA = fmaf(__uint_as_float(u1 & 0xffff0000u), cn0.y, denA);
                denA = fmaf(__uint_as_float(u2 & 0xffff0000u), cn0.z, denA);
                denA = fmaf(__uint_as_float(u3 & 0xffff0000u), cn0.w, denA);
                denA = fmaf(__uint_as_float(u4 & 0xffff0000u), cn1.x, denA);
                denA = fmaf(__uint_as_float(u5 & 0xffff0000u), cn1.y, denA);
                denA = fmaf(__uint_as_float(u6 & 0xffff0000u), cn1.z, denA);
                denA = fmaf(__uint_as_float(u7 & 0xffff0000u), cn1.w, denA);
                paA.u[0] = pk_hi16(u1, u0);
                paA.u[1] = pk_hi16(u3, u2);
                paA.u[2] = pk_hi16(u5, u4);
                paA.u[3] = pk_hi16(u7, u6);
            }
            {
                unsigned u0 = __float_as_uint(__expf(sB0[0]));
                unsigned u1 = __float_as_uint(__expf(sB0[1]));
                unsigned u2 = __float_as_uint(__expf(sB0[2]));
                unsigned u3 = __float_as_uint(__expf(sB0[3]));
                unsigned u4 = __float_as_uint(__expf(sB1[0]));
                unsigned u5 = __float_as_uint(__expf(sB1[1]));
                unsigned u6 = __float_as_uint(__expf(sB1[2]));
                unsigned u7 = __float_as_uint(__expf(sB1[3]));
                denB = fmaf(__uint_as_float(u0 & 0xffff0000u), cn0.x, denB);
                denB = fmaf(__uint_as_float(u1 & 0xffff0000u), cn0.y, denB);
                denB = fmaf(__uint_as_float(u2 & 0xffff0000u), cn0.z, denB);
                denB = fmaf(__uint_as_float(u3 & 0xffff0000u), cn0.w, denB);
                denB = fmaf(__uint_as_float(u4 & 0xffff0000u), cn1.x, denB);
                denB = fmaf(__uint_as_float(u5 & 0xffff0000u), cn1.y, denB);
                denB = fmaf(__uint_as_float(u6 & 0xffff0000u), cn1.z, denB);
                denB = fmaf(__uint_as_float(u7 & 0xffff0000u), cn1.w, denB);
                paB.u[0] = pk_hi16(u1, u0);
                paB.u[1] = pk_hi16(u3, u2);
                paB.u[2] = pk_hi16(u5, u4);
                paB.u[3] = pk_hi16(u7, u6);
            }
            oA = __builtin_amdgcn_mfma_f32_16x16x32_bf16(paA.s8, mb, oA, 0, 0, 0);
            oB = __builtin_amdgcn_mfma_f32_16x16x32_bf16(paB.s8, mb, oB, 0, 0, 0);
        }
        // den: sum the 4 g-groups (lane-local partial covers 8 of 32 codes/blk)
        denA += __shfl_xor(denA, 16, 64);
        denA += __shfl_xor(denA, 32, 64);
        denB += __shfl_xor(denB, 16, 64);
        denB += __shfl_xor(denB, 32, 64);
#pragma unroll
        for (int r = 0; r < 4; ++r) {
            int row = g * 4 + r;                       // token index (PV acc row)
            float dA = __shfl(denA, row, 64);          // den[token] lives at lane&15==token
            float dB = __shfl(denB, row, 64);
            out[(size_t)(tokA + row) * D16 + col] = oA[r] / (dA + 1e-15f);
            out[(size_t)(tokB + row) * D16 + col] = oB[r] / (dB + 1e-15f);
        }
    }
}

extern "C" void kernel_launch(void* const* d_in, const int* in_sizes, int n_in,
                              void* d_out, int out_size, void* d_ws, size_t ws_size,
                              hipStream_t stream) {
    const float* qkv = (const float*)d_in[0];   // (8, 384, 64, 64) fp32
    const float* cb  = (const float*)d_in[1];   // (512, 16) fp32
    float* out = (float*)d_out;                 // (8, 128, 64, 64) fp32

    float* M = (float*)d_ws;                                   // K x 17 fp32
    unsigned short* idx = (unsigned short*)((char*)d_ws + 36864);

    hipMemsetAsync(d_ws, 0, KC * 17 * sizeof(float), stream);

    vq_assign<<<NTOK / 256, 256, 0, stream>>>(qkv, cb, idx);
    vq_segsum<<<NTOK / 512, 256, 0, stream>>>(qkv, idx, M);
    vq_attend<<<NTOK / 256, 256, 0, stream>>>(qkv, cb, M, out);
}